// Round 5
// baseline (137.881 us; speedup 1.0000x reference)
//
#include <hip/hip_runtime.h>
#include <hip/hip_bf16.h>

#define MD 128   // D
#define KC 8     // K capsules
#define KD 16    // DD
#define MN 16    // M neighbors
#define QS 20    // LDS row stride (floats): 16B-aligned, bank-spread

static __device__ __forceinline__ float lo_bf(unsigned int w){ union{unsigned int i;float f;}c; c.i=w<<16;        return c.f; }
static __device__ __forceinline__ float hi_bf(unsigned int w){ union{unsigned int i;float f;}c; c.i=w&0xffff0000u; return c.f; }
static __device__ __forceinline__ float bf2f1(unsigned short u){ union{unsigned int i;float f;}c; c.i=((unsigned int)u)<<16; return c.f; }

static __device__ __forceinline__ float fast_rsq(float x){ return __builtin_amdgcn_rsqf(x); }
static __device__ __forceinline__ float fast_rcp(float x){ return __builtin_amdgcn_rcpf(x); }

// ---- packed f16 min/max on raw bf16 bit pairs (inline asm: guaranteed VOP3P) ----
// Valid because: f16 min/max order == u16 sign-magnitude order == bf16 value
// order, as long as no operand has bits in the f16 NaN/Inf range (>=0x7C00,
// i.e. |bf16| >= ~1e17). Inputs are randn (|x| <= ~6) -> huge margin.
static __device__ __forceinline__ unsigned pkmin(unsigned a, unsigned b) {
    unsigned d; asm("v_pk_min_f16 %0, %1, %2" : "=v"(d) : "v"(a), "v"(b)); return d;
}
static __device__ __forceinline__ unsigned pkmax(unsigned a, unsigned b) {
    unsigned d; asm("v_pk_max_f16 %0, %1, %2" : "=v"(d) : "v"(a), "v"(b)); return d;
}
static __device__ __forceinline__ uint2 pmin2(uint2 a, uint2 b) {
    uint2 r; r.x = pkmin(a.x, b.x); r.y = pkmin(a.y, b.y); return r;
}
static __device__ __forceinline__ uint2 pmax2(uint2 a, uint2 b) {
    uint2 r; r.x = pkmax(a.x, b.x); r.y = pkmax(a.y, b.y); return r;
}
static __device__ __forceinline__ void pcas2(uint2& x, uint2& y) {
    uint2 lo = pmin2(x, y), hi = pmax2(x, y); x = lo; y = hi;
}
// Batcher odd-even mergesort, 8 elems, 19 CAS — FOUR columns per CAS (uint2 of bf16x2)
static __device__ __forceinline__ void psort8(uint2 a[8]) {
    pcas2(a[0],a[1]); pcas2(a[2],a[3]); pcas2(a[4],a[5]); pcas2(a[6],a[7]);
    pcas2(a[0],a[2]); pcas2(a[1],a[3]); pcas2(a[4],a[6]); pcas2(a[5],a[7]);
    pcas2(a[1],a[2]); pcas2(a[5],a[6]);
    pcas2(a[0],a[4]); pcas2(a[2],a[6]); pcas2(a[2],a[4]);
    pcas2(a[1],a[5]); pcas2(a[3],a[7]); pcas2(a[3],a[5]);
    pcas2(a[1],a[2]); pcas2(a[3],a[4]); pcas2(a[5],a[6]);
}
// b7/b8 (8th/9th smallest of 16) per column via merged-rank identity
static __device__ __forceinline__ void pmed16(uint2 a[16], uint2& b7, uint2& b8) {
    psort8(a); psort8(a + 8);
    const uint2* u = a; const uint2* v = a + 8;
    uint2 t7 =             pmin2(u[7], v[0]);
    t7 = pmax2(t7, pmin2(u[6], v[1]));
    t7 = pmax2(t7, pmin2(u[5], v[2]));
    t7 = pmax2(t7, pmin2(u[4], v[3]));
    t7 = pmax2(t7, pmin2(u[3], v[4]));
    t7 = pmax2(t7, pmin2(u[2], v[5]));
    t7 = pmax2(t7, pmin2(u[1], v[6]));
    t7 = pmax2(t7, pmin2(u[0], v[7]));
    uint2 t8 = pmax2(u[0], v[0]);
    t8 = pmax2(t8, pmin2(u[7], v[1]));
    t8 = pmax2(t8, pmin2(u[6], v[2]));
    t8 = pmax2(t8, pmin2(u[5], v[3]));
    t8 = pmax2(t8, pmin2(u[4], v[4]));
    t8 = pmax2(t8, pmin2(u[3], v[5]));
    t8 = pmax2(t8, pmin2(u[2], v[6]));
    t8 = pmax2(t8, pmin2(u[1], v[7]));
    b7 = t7; b8 = t8;
}

// ---- scalar f32 median (f32-dtype fallback path) ----
static __device__ __forceinline__ void cas(float& x, float& y) {
    float lo = fminf(x, y), hi = fmaxf(x, y); x = lo; y = hi;
}
static __device__ __forceinline__ void sort8f(float a[8]) {
    cas(a[0],a[1]); cas(a[2],a[3]); cas(a[4],a[5]); cas(a[6],a[7]);
    cas(a[0],a[2]); cas(a[1],a[3]); cas(a[4],a[6]); cas(a[5],a[7]);
    cas(a[1],a[2]); cas(a[5],a[6]);
    cas(a[0],a[4]); cas(a[2],a[6]); cas(a[2],a[4]);
    cas(a[1],a[5]); cas(a[3],a[7]); cas(a[3],a[5]);
    cas(a[1],a[2]); cas(a[3],a[4]); cas(a[5],a[6]);
}
static __device__ __forceinline__ float med17f(float a[16], float self) {
    sort8f(a); sort8f(a + 8);
    const float* u = a; const float* v = a + 8;
    float t7 =            fminf(u[7], v[0]);
    t7 = fmaxf(t7, fminf(u[6], v[1])); t7 = fmaxf(t7, fminf(u[5], v[2]));
    t7 = fmaxf(t7, fminf(u[4], v[3])); t7 = fmaxf(t7, fminf(u[3], v[4]));
    t7 = fmaxf(t7, fminf(u[2], v[5])); t7 = fmaxf(t7, fminf(u[1], v[6]));
    t7 = fmaxf(t7, fminf(u[0], v[7]));
    float t8 = fmaxf(u[0], v[0]);
    t8 = fmaxf(t8, fminf(u[7], v[1])); t8 = fmaxf(t8, fminf(u[6], v[2]));
    t8 = fmaxf(t8, fminf(u[5], v[3])); t8 = fmaxf(t8, fminf(u[4], v[4]));
    t8 = fmaxf(t8, fminf(u[3], v[5])); t8 = fmaxf(t8, fminf(u[2], v[6]));
    t8 = fmaxf(t8, fminf(u[1], v[7]));
    return __builtin_amdgcn_fmed3f(self, t7, t8);
}

// full-rate VALU lane exchange via DPP
template<int CTRL>
static __device__ __forceinline__ float dpp_mov(float v) {
    return __int_as_float(__builtin_amdgcn_update_dpp(
        0, __float_as_int(v), CTRL, 0xF, 0xF, false));
}
static __device__ __forceinline__ float rsum_quad(float v) {
    v += dpp_mov<0xB1>(v);   // quad_perm xor1
    v += dpp_mov<0x4E>(v);   // quad_perm xor2
    return v;
}
static __device__ __forceinline__ float rsum_caps(float v) {
    v += __shfl_xor(v, 4);
    v += dpp_mov<0x128>(v);  // row_ror:8 == xor8
    v += __shfl_xor(v, 16);
    return v;
}
static __device__ __forceinline__ float rmax_caps(float v) {
    v = fmaxf(v, __shfl_xor(v, 4));
    v = fmaxf(v, dpp_mov<0x128>(v));
    v = fmaxf(v, __shfl_xor(v, 16));
    return v;
}

// flag[0] = 1 if h is bf16, 0 if f32
__global__ void detect_dtype(const unsigned short* __restrict__ h, int* __restrict__ flag) {
    int l = threadIdx.x;
    float m = 0.f;
    for (int i = l; i < 1024; i += 64) {
        float v = bf2f1(h[i]);
        v = (v != v) ? 1e30f : fabsf(v);
        m = fmaxf(m, v);
    }
    #pragma unroll
    for (int off = 1; off < 64; off <<= 1) m = fmaxf(m, __shfl_xor(m, off));
    if (l == 0) flag[0] = (m < 1000.0f) ? 1 : 0;
}

template<bool BF>
__global__ __launch_bounds__(256)
void attn_fwd(const void* __restrict__ hraw,
              const int* __restrict__ nbr,
              const void* __restrict__ qry,
              const void* __restrict__ keyw,
              const int* __restrict__ iterat_p,
              const int* __restrict__ flag_p,
              void* __restrict__ out,
              int n_nodes)
{
    if (flag_p[0] != (BF ? 1 : 0)) return;  // uniform exit before the barrier

    const int tid  = threadIdx.x;
    const int wid  = tid >> 6;
    const int l    = tid & 63;
    const int sub  = l & 31;
    const int half = (l >> 5) & 1;
    const int k    = sub >> 2;
    const int q4   = sub & 3;

    // block-shared Q (row-major) and K^T, staged ONCE
    __shared__ float qs[16 * QS];
    __shared__ float kts[16 * QS];
    if (tid < 64) {
        float4 qv, kv;
        if (BF) {
            uint2 qw = ((const uint2*)qry)[tid];
            uint2 kw = ((const uint2*)keyw)[tid];
            qv.x = lo_bf(qw.x); qv.y = hi_bf(qw.x); qv.z = lo_bf(qw.y); qv.w = hi_bf(qw.y);
            kv.x = lo_bf(kw.x); kv.y = hi_bf(kw.x); kv.z = lo_bf(kw.y); kv.w = hi_bf(kw.y);
        } else {
            qv = ((const float4*)qry)[tid];
            kv = ((const float4*)keyw)[tid];
        }
        int e = tid >> 2, f0 = (tid & 3) * 4;
        *(float4*)&qs[e * QS + f0] = qv;
        kts[(f0 + 0) * QS + e] = kv.x;
        kts[(f0 + 1) * QS + e] = kv.y;
        kts[(f0 + 2) * QS + e] = kv.z;
        kts[(f0 + 3) * QS + e] = kv.w;
    }
    __syncthreads();   // the only barrier; everything after is barrier-free

    const int iterat = iterat_p[0];
    const int vb = half << 6;   // ds_bpermute byte base: lane half*16

    for (int base = blockIdx.x * 8; base < n_nodes; base += gridDim.x * 8) {
        int n = base + wid * 2 + half;
        if (n >= n_nodes) n = n_nodes - 1;   // duplicate work, identical writes

        // ---- load neighbor indices (lanes 0-15: node A, 16-31: node B) ----
        int nnb = base + wid * 2 + ((l >> 4) & 1);
        if (nnb >= n_nodes) nnb = n_nodes - 1;
        const int nbv = nbr[nnb * MN + (l & 15)];

        // ---- self row ----
        uint2 hp_b; float4 hp_f;
        if (BF) hp_b = ((const uint2*)hraw)[(size_t)n * 32 + sub];
        else    hp_f = ((const float4*)hraw)[(size_t)n * 32 + sub];

        // ---- gather 16 rows: ds_bpermute idx broadcast + 32-bit voffset ----
        uint2  rb[16]; float4 rf[16];
        #pragma unroll
        for (int m = 0; m < MN; ++m) {
            int idx = __builtin_amdgcn_ds_bpermute(vb + m * 4, nbv);
            if (BF) rb[m] = *(const uint2*) ((const char*)hraw + (((unsigned)idx << 8) + (unsigned)sub * 8u));
            else    rf[m] = *(const float4*)((const char*)hraw + (((unsigned)idx << 9) + (unsigned)sub * 16u));
        }

        // ---- self normalize (4 dims/lane) ----
        float hp[4];
        if (BF) { hp[0]=lo_bf(hp_b.x); hp[1]=hi_bf(hp_b.x); hp[2]=lo_bf(hp_b.y); hp[3]=hi_bf(hp_b.y); }
        else    { hp[0]=hp_f.x; hp[1]=hp_f.y; hp[2]=hp_f.z; hp[3]=hp_f.w; }
        float ss = 0;
        #pragma unroll
        for (int i = 0; i < 4; ++i) ss = fmaf(hp[i], hp[i], ss);
        ss = rsum_quad(ss);
        float inv = fast_rsq(fmaxf(ss, 1e-24f));
        float hc[4];
        #pragma unroll
        for (int i = 0; i < 4; ++i) hc[i] = hp[i] * inv;

        // ---- kk = hc @ K ; w = Q @ kk (quad DPP broadcasts + LDS rows) ----
        float hcA[4][4];
        #pragma unroll
        for (int j = 0; j < 4; ++j) {
            hcA[0][j] = dpp_mov<0x00>(hc[j]); hcA[1][j] = dpp_mov<0x55>(hc[j]);
            hcA[2][j] = dpp_mov<0xAA>(hc[j]); hcA[3][j] = dpp_mov<0xFF>(hc[j]);
        }
        float kk[4];
        #pragma unroll
        for (int i = 0; i < 4; ++i) {
            const float* row = &kts[(q4 * 4 + i) * QS];
            float acc = 0;
            #pragma unroll
            for (int r = 0; r < 4; ++r) {
                float4 kr = *(const float4*)(row + r * 4);
                acc = fmaf(hcA[r][0], kr.x, acc); acc = fmaf(hcA[r][1], kr.y, acc);
                acc = fmaf(hcA[r][2], kr.z, acc); acc = fmaf(hcA[r][3], kr.w, acc);
            }
            kk[i] = acc;
        }
        float kkA[4][4];
        #pragma unroll
        for (int j = 0; j < 4; ++j) {
            kkA[0][j] = dpp_mov<0x00>(kk[j]); kkA[1][j] = dpp_mov<0x55>(kk[j]);
            kkA[2][j] = dpp_mov<0xAA>(kk[j]); kkA[3][j] = dpp_mov<0xFF>(kk[j]);
        }
        float w[4];
        #pragma unroll
        for (int i = 0; i < 4; ++i) {
            const float* row = &qs[(q4 * 4 + i) * QS];
            float acc = 0;
            #pragma unroll
            for (int r = 0; r < 4; ++r) {
                float4 qr = *(const float4*)(row + r * 4);
                acc = fmaf(kkA[r][0], qr.x, acc); acc = fmaf(kkA[r][1], qr.y, acc);
                acc = fmaf(kkA[r][2], qr.z, acc); acc = fmaf(kkA[r][3], qr.w, acc);
            }
            w[i] = acc;
        }

        // ---- att = softmax_k(hc . w) ----
        float lg = 0;
        #pragma unroll
        for (int i = 0; i < 4; ++i) lg = fmaf(hc[i], w[i], lg);
        float logit = rsum_quad(lg);
        float mx  = rmax_caps(logit);
        float ex  = __expf(logit - mx);
        float att = ex * fast_rcp(rsum_caps(ex));

        // ---- column sums over the 16 gathered rows (before in-place sort) ----
        float sn[4] = {0,0,0,0}, s2[4] = {0,0,0,0};
        #pragma unroll
        for (int m = 0; m < 16; ++m) {
            float x0, x1, x2, x3;
            if (BF) { x0=lo_bf(rb[m].x); x1=hi_bf(rb[m].x); x2=lo_bf(rb[m].y); x3=hi_bf(rb[m].y); }
            else    { x0=rf[m].x; x1=rf[m].y; x2=rf[m].z; x3=rf[m].w; }
            sn[0]+=x0; sn[1]+=x1; sn[2]+=x2; sn[3]+=x3;
            s2[0]=fmaf(x0,x0,s2[0]); s2[1]=fmaf(x1,x1,s2[1]);
            s2[2]=fmaf(x2,x2,s2[2]); s2[3]=fmaf(x3,x3,s2[3]);
        }

        // ---- medians: packed f16 CAS in place on raw bf16 words (no keying) ----
        float mid[4];
        if (BF) {
            uint2 b7, b8;
            pmed16(rb, b7, b8);
            mid[0] = __builtin_amdgcn_fmed3f(hc[0], lo_bf(b7.x), lo_bf(b8.x));
            mid[1] = __builtin_amdgcn_fmed3f(hc[1], hi_bf(b7.x), hi_bf(b8.x));
            mid[2] = __builtin_amdgcn_fmed3f(hc[2], lo_bf(b7.y), lo_bf(b8.y));
            mid[3] = __builtin_amdgcn_fmed3f(hc[3], hi_bf(b7.y), hi_bf(b8.y));
        } else {
            #pragma unroll
            for (int c = 0; c < 4; ++c) {
                float a[16];
                #pragma unroll
                for (int m = 0; m < 16; ++m)
                    a[m] = (c==0) ? rf[m].x : (c==1) ? rf[m].y : (c==2) ? rf[m].z : rf[m].w;
                mid[c] = med17f(a, hc[c]);
            }
        }
        #pragma unroll
        for (int c = 0; c < 4; ++c) {
            float t2 = fmaf(hc[c], hc[c], s2[c]);
            mid[c] *= fast_rsq(fmaxf(t2, 1e-24f));
        }

        // diag[k] = (sum_m nb[m,k]) . w[k]
        float dgl = 0;
        #pragma unroll
        for (int i = 0; i < 4; ++i) dgl = fmaf(sn[i], w[i], dgl);
        float dg = rsum_quad(dgl);

        // cov_d = sum_k diag[k]*(hc-mid)^2  (row-independent)
        float cv[4];
        #pragma unroll
        for (int i = 0; i < 4; ++i) {
            float t = hc[i] - mid[i];
            cv[i] = rsum_caps(dg * t * t);
        }

        // dets/left, exact NaN semantics of the reference
        float lsl = 0;
        #pragma unroll
        for (int i = 0; i < 4; ++i) {
            float lr = __logf(cv[i]);
            lr = (lr != lr) ? 1e-6f : lr;
            lsl += __logf(lr);
        }
        float ls   = rsum_quad(lsl);
        float dets = __expf(ls);
        const float coef = 5.822108e-7f;  // 1/sqrt((2*pi)^16 / 2)
        float left = coef * fast_rsq(dets + 1e-6f);

        // ---- iterative routing ----
        float ah[4], ix[4];
        #pragma unroll
        for (int i = 0; i < 4; ++i) ah[i] = att * hc[i];
        #pragma unroll
        for (int i = 0; i < 4; ++i) ix[i] = rsum_caps(ah[i]);

        for (int it = 0; it < iterat; ++it) {
            float rsl = 0;
            #pragma unroll
            for (int i = 0; i < 4; ++i) {
                float df = ix[i] - hc[i];
                rsl = fmaf(cv[i] * df, df, rsl);
            }
            float rs   = rsum_quad(rsl);
            float prob = left * __expf(-0.5f * rs);
            float p2   = rsum_caps(prob * prob);
            float pn   = prob * fast_rsq(fmaxf(p2, 1e-24f));
            pn = (pn != pn) ? 1e-6f : pn;
            float den = rsum_caps(att * pn);
            float num[4];
            #pragma unroll
            for (int i = 0; i < 4; ++i) num[i] = rsum_caps(pn * ah[i]);
            float rr = fast_rcp(den + 1e-9f);
            #pragma unroll
            for (int i = 0; i < 4; ++i) ix[i] = num[i] * rr;
        }

        // ---- x = normalize(ix); write outputs ----
        float xs = 0;
        #pragma unroll
        for (int i = 0; i < 4; ++i) xs = fmaf(ix[i], ix[i], xs);
        xs = rsum_quad(xs);
        float xinv = fast_rsq(fmaxf(xs, 1e-24f));

        if (BF) {
            if (sub < 4) {
                __hip_bfloat16 b0 = __float2bfloat16(ix[0] * xinv);
                __hip_bfloat16 b1 = __float2bfloat16(ix[1] * xinv);
                __hip_bfloat16 b2 = __float2bfloat16(ix[2] * xinv);
                __hip_bfloat16 b3 = __float2bfloat16(ix[3] * xinv);
                uint2 o;
                o.x = (unsigned)(*(unsigned short*)&b0) | ((unsigned)(*(unsigned short*)&b1) << 16);
                o.y = (unsigned)(*(unsigned short*)&b2) | ((unsigned)(*(unsigned short*)&b3) << 16);
                *(uint2*)((char*)out + (size_t)n * 32 + q4 * 8) = o;
            }
            if (q4 == 0) {
                __hip_bfloat16 ba = __float2bfloat16(att);
                ((unsigned short*)out)[(size_t)n_nodes * KD + (size_t)n * KC + k] =
                    *(unsigned short*)&ba;
            }
        } else {
            if (sub < 4) {
                float4 o;
                o.x = ix[0] * xinv; o.y = ix[1] * xinv; o.z = ix[2] * xinv; o.w = ix[3] * xinv;
                *(float4*)((float*)out + (size_t)n * KD + q4 * 4) = o;
            }
            if (q4 == 0) ((float*)out)[(size_t)n_nodes * KD + (size_t)n * KC + k] = att;
        }
    }
}

extern "C" void kernel_launch(void* const* d_in, const int* in_sizes, int n_in,
                              void* d_out, int out_size, void* d_ws, size_t ws_size,
                              hipStream_t stream) {
    const void* h    = d_in[0];
    const int*  nbr  = (const int*)d_in[1];
    const void* qry  = d_in[2];
    const void* keyw = (const void*)d_in[3];
    const int*  iterat_p = (const int*)d_in[4];

    int n_nodes = in_sizes[0] / MD;
    int* flag = (int*)d_ws;

    detect_dtype<<<1, 64, 0, stream>>>((const unsigned short*)h, flag);

    int full = (n_nodes + 7) / 8;               // 8 nodes/block; bf16 covers all in 1 pass
    int small = full < 1024 ? full : 1024;      // dead path exits fast; grid-strided if live
    attn_fwd<true ><<<full,  256, 0, stream>>>(h, nbr, qry, keyw, iterat_p, flag, d_out, n_nodes);
    attn_fwd<false><<<small, 256, 0, stream>>>(h, nbr, qry, keyw, iterat_p, flag, d_out, n_nodes);
}

// Round 6
// 101.726 us; speedup vs baseline: 1.3554x; 1.3554x over previous
//
#include <hip/hip_runtime.h>
#include <hip/hip_bf16.h>

#define MD 128   // D
#define KC 8     // K capsules
#define KD 16    // DD
#define MN 16    // M neighbors
#define QS 20    // LDS row stride (floats): 16B-aligned, bank-spread

typedef float    f32x2 __attribute__((ext_vector_type(2)));
typedef float    f32x4 __attribute__((ext_vector_type(4)));
typedef _Float16 f16x2 __attribute__((ext_vector_type(2)));

static __device__ __forceinline__ float lo_bf(unsigned int w){ union{unsigned int i;float f;}c; c.i=w<<16;        return c.f; }
static __device__ __forceinline__ float hi_bf(unsigned int w){ union{unsigned int i;float f;}c; c.i=w&0xffff0000u; return c.f; }
static __device__ __forceinline__ float bf2f1(unsigned short u){ union{unsigned int i;float f;}c; c.i=((unsigned int)u)<<16; return c.f; }

static __device__ __forceinline__ float fast_rsq(float x){ return __builtin_amdgcn_rsqf(x); }
static __device__ __forceinline__ float fast_rcp(float x){ return __builtin_amdgcn_rcpf(x); }

// ---- packed f16 min/max on raw bf16 bit pairs (builtins -> v_pk_min/max_f16,
// no asm: compiler keeps scheduling + regalloc freedom).
// Order-exact: f16 compare order == u16 sign-magnitude order == bf16 value
// order while no operand is in the f16 NaN/Inf bit range (|bf16| >= ~1e17).
static __device__ __forceinline__ unsigned phmin(unsigned a, unsigned b) {
    return __builtin_bit_cast(unsigned, __builtin_elementwise_min(
        __builtin_bit_cast(f16x2, a), __builtin_bit_cast(f16x2, b)));
}
static __device__ __forceinline__ unsigned phmax(unsigned a, unsigned b) {
    return __builtin_bit_cast(unsigned, __builtin_elementwise_max(
        __builtin_bit_cast(f16x2, a), __builtin_bit_cast(f16x2, b)));
}
static __device__ __forceinline__ void pcas(unsigned& x, unsigned& y) {
    unsigned lo = phmin(x, y), hi = phmax(x, y); x = lo; y = hi;
}
// Batcher odd-even mergesort, 8 elems, 19 CAS — two bf16 columns per op
static __device__ __forceinline__ void psort8(unsigned a[8]) {
    pcas(a[0],a[1]); pcas(a[2],a[3]); pcas(a[4],a[5]); pcas(a[6],a[7]);
    pcas(a[0],a[2]); pcas(a[1],a[3]); pcas(a[4],a[6]); pcas(a[5],a[7]);
    pcas(a[1],a[2]); pcas(a[5],a[6]);
    pcas(a[0],a[4]); pcas(a[2],a[6]); pcas(a[2],a[4]);
    pcas(a[1],a[5]); pcas(a[3],a[7]); pcas(a[3],a[5]);
    pcas(a[1],a[2]); pcas(a[3],a[4]); pcas(a[5],a[6]);
}
// b7/b8 (8th/9th smallest of 16) per packed column via merged-rank identity
static __device__ __forceinline__ void pmed16(unsigned a[16], unsigned& b7, unsigned& b8) {
    psort8(a); psort8(a + 8);
    const unsigned* u = a; const unsigned* v = a + 8;
    unsigned t7 =             phmin(u[7], v[0]);
    t7 = phmax(t7, phmin(u[6], v[1]));
    t7 = phmax(t7, phmin(u[5], v[2]));
    t7 = phmax(t7, phmin(u[4], v[3]));
    t7 = phmax(t7, phmin(u[3], v[4]));
    t7 = phmax(t7, phmin(u[2], v[5]));
    t7 = phmax(t7, phmin(u[1], v[6]));
    t7 = phmax(t7, phmin(u[0], v[7]));
    unsigned t8 = phmax(u[0], v[0]);
    t8 = phmax(t8, phmin(u[7], v[1]));
    t8 = phmax(t8, phmin(u[6], v[2]));
    t8 = phmax(t8, phmin(u[5], v[3]));
    t8 = phmax(t8, phmin(u[4], v[4]));
    t8 = phmax(t8, phmin(u[3], v[5]));
    t8 = phmax(t8, phmin(u[2], v[6]));
    t8 = phmax(t8, phmin(u[1], v[7]));
    b7 = t7; b8 = t8;
}

// ---- scalar f32 median (f32-dtype fallback path) ----
static __device__ __forceinline__ void cas(float& x, float& y) {
    float lo = fminf(x, y), hi = fmaxf(x, y); x = lo; y = hi;
}
static __device__ __forceinline__ void sort8f(float a[8]) {
    cas(a[0],a[1]); cas(a[2],a[3]); cas(a[4],a[5]); cas(a[6],a[7]);
    cas(a[0],a[2]); cas(a[1],a[3]); cas(a[4],a[6]); cas(a[5],a[7]);
    cas(a[1],a[2]); cas(a[5],a[6]);
    cas(a[0],a[4]); cas(a[2],a[6]); cas(a[2],a[4]);
    cas(a[1],a[5]); cas(a[3],a[7]); cas(a[3],a[5]);
    cas(a[1],a[2]); cas(a[3],a[4]); cas(a[5],a[6]);
}
static __device__ __forceinline__ float med17f(float a[16], float self) {
    sort8f(a); sort8f(a + 8);
    const float* u = a; const float* v = a + 8;
    float t7 =            fminf(u[7], v[0]);
    t7 = fmaxf(t7, fminf(u[6], v[1])); t7 = fmaxf(t7, fminf(u[5], v[2]));
    t7 = fmaxf(t7, fminf(u[4], v[3])); t7 = fmaxf(t7, fminf(u[3], v[4]));
    t7 = fmaxf(t7, fminf(u[2], v[5])); t7 = fmaxf(t7, fminf(u[1], v[6]));
    t7 = fmaxf(t7, fminf(u[0], v[7]));
    float t8 = fmaxf(u[0], v[0]);
    t8 = fmaxf(t8, fminf(u[7], v[1])); t8 = fmaxf(t8, fminf(u[6], v[2]));
    t8 = fmaxf(t8, fminf(u[5], v[3])); t8 = fmaxf(t8, fminf(u[4], v[4]));
    t8 = fmaxf(t8, fminf(u[3], v[5])); t8 = fmaxf(t8, fminf(u[2], v[6]));
    t8 = fmaxf(t8, fminf(u[1], v[7]));
    return __builtin_amdgcn_fmed3f(self, t7, t8);
}

// full-rate VALU lane exchange via DPP
template<int CTRL>
static __device__ __forceinline__ float dpp_mov(float v) {
    return __int_as_float(__builtin_amdgcn_update_dpp(
        0, __float_as_int(v), CTRL, 0xF, 0xF, false));
}
static __device__ __forceinline__ float rsum_quad(float v) {
    v += dpp_mov<0xB1>(v);   // quad_perm xor1
    v += dpp_mov<0x4E>(v);   // quad_perm xor2
    return v;
}
static __device__ __forceinline__ float rsum_caps(float v) {
    v += __shfl_xor(v, 4);
    v += dpp_mov<0x128>(v);  // row_ror:8 == xor8
    v += __shfl_xor(v, 16);
    return v;
}
static __device__ __forceinline__ float rmax_caps(float v) {
    v = fmaxf(v, __shfl_xor(v, 4));
    v = fmaxf(v, dpp_mov<0x128>(v));
    v = fmaxf(v, __shfl_xor(v, 16));
    return v;
}

// flag[0] = 1 if h is bf16, 0 if f32
__global__ void detect_dtype(const unsigned short* __restrict__ h, int* __restrict__ flag) {
    int l = threadIdx.x;
    float m = 0.f;
    for (int i = l; i < 1024; i += 64) {
        float v = bf2f1(h[i]);
        v = (v != v) ? 1e30f : fabsf(v);
        m = fmaxf(m, v);
    }
    #pragma unroll
    for (int off = 1; off < 64; off <<= 1) m = fmaxf(m, __shfl_xor(m, off));
    if (l == 0) flag[0] = (m < 1000.0f) ? 1 : 0;
}

template<bool BF>
__global__ __launch_bounds__(256)
void attn_fwd(const void* __restrict__ hraw,
              const int* __restrict__ nbr,
              const void* __restrict__ qry,
              const void* __restrict__ keyw,
              const int* __restrict__ iterat_p,
              const int* __restrict__ flag_p,
              void* __restrict__ out,
              int n_nodes)
{
    if (flag_p[0] != (BF ? 1 : 0)) return;  // uniform exit before the barrier

    const int tid  = threadIdx.x;
    const int wid  = tid >> 6;
    const int l    = tid & 63;
    const int sub  = l & 31;
    const int half = (l >> 5) & 1;
    const int k    = sub >> 2;
    const int q4   = sub & 3;

    // block-shared Q (row-major) and K^T, staged ONCE
    __shared__ float qs[16 * QS];
    __shared__ float kts[16 * QS];
    if (tid < 64) {
        float4 qv, kv;
        if (BF) {
            uint2 qw = ((const uint2*)qry)[tid];
            uint2 kw = ((const uint2*)keyw)[tid];
            qv.x = lo_bf(qw.x); qv.y = hi_bf(qw.x); qv.z = lo_bf(qw.y); qv.w = hi_bf(qw.y);
            kv.x = lo_bf(kw.x); kv.y = hi_bf(kw.x); kv.z = lo_bf(kw.y); kv.w = hi_bf(kw.y);
        } else {
            qv = ((const float4*)qry)[tid];
            kv = ((const float4*)keyw)[tid];
        }
        int e = tid >> 2, f0 = (tid & 3) * 4;
        *(float4*)&qs[e * QS + f0] = qv;
        kts[(f0 + 0) * QS + e] = kv.x;
        kts[(f0 + 1) * QS + e] = kv.y;
        kts[(f0 + 2) * QS + e] = kv.z;
        kts[(f0 + 3) * QS + e] = kv.w;
    }
    __syncthreads();   // the only barrier

    const int iterat = iterat_p[0];

    for (int base = blockIdx.x * 8; base < n_nodes; base += gridDim.x * 8) {
        int n = base + wid * 2 + half;
        if (n >= n_nodes) n = n_nodes - 1;   // duplicate work, identical writes

        // ---- neighbor indices (lanes 0-15: node A, 16-31: node B) ----
        int nnb = base + wid * 2 + ((l >> 4) & 1);
        if (nnb >= n_nodes) nnb = n_nodes - 1;
        const int nbv = nbr[nnb * MN + (l & 15)];

        // ---- self row ----
        uint2 hp_b; float4 hp_f;
        if (BF) hp_b = ((const uint2*)hraw)[(size_t)n * 32 + sub];
        else    hp_f = ((const float4*)hraw)[(size_t)n * 32 + sub];

        // ---- 16-row gather (SGPR idx via readlane, 32-bit voffset) ----
        uint2  rb[16]; float4 rf[16];
        #pragma unroll
        for (int m = 0; m < MN; ++m) {
            int ia  = __builtin_amdgcn_readlane(nbv, m);
            int ib  = __builtin_amdgcn_readlane(nbv, m + 16);
            int idx = half ? ib : ia;
            if (BF) rb[m] = *(const uint2*) ((const char*)hraw + (((unsigned)idx << 8) + (unsigned)sub * 8u));
            else    rf[m] = *(const float4*)((const char*)hraw + (((unsigned)idx << 9) + (unsigned)sub * 16u));
        }

        // ---- self normalize: packed f32 pairs ----
        f32x2 hp2[2];
        if (BF) { hp2[0] = f32x2{lo_bf(hp_b.x), hi_bf(hp_b.x)};
                  hp2[1] = f32x2{lo_bf(hp_b.y), hi_bf(hp_b.y)}; }
        else    { hp2[0] = f32x2{hp_f.x, hp_f.y}; hp2[1] = f32x2{hp_f.z, hp_f.w}; }
        f32x2 ss2 = hp2[0] * hp2[0] + hp2[1] * hp2[1];
        float ss  = rsum_quad(ss2.x + ss2.y);
        float inv = fast_rsq(fmaxf(ss, 1e-24f));
        f32x2 hc2[2] = { hp2[0] * inv, hp2[1] * inv };
        float hcs[4] = { hc2[0].x, hc2[0].y, hc2[1].x, hc2[1].y };

        // ---- kk = hc @ K (quad DPP broadcast + packed LDS FMA) ----
        f32x2 bc[4][2];
        #pragma unroll
        for (int j = 0; j < 2; ++j) {
            bc[0][j] = f32x2{dpp_mov<0x00>(hcs[2*j]), dpp_mov<0x00>(hcs[2*j+1])};
            bc[1][j] = f32x2{dpp_mov<0x55>(hcs[2*j]), dpp_mov<0x55>(hcs[2*j+1])};
            bc[2][j] = f32x2{dpp_mov<0xAA>(hcs[2*j]), dpp_mov<0xAA>(hcs[2*j+1])};
            bc[3][j] = f32x2{dpp_mov<0xFF>(hcs[2*j]), dpp_mov<0xFF>(hcs[2*j+1])};
        }
        float kkv[4];
        #pragma unroll
        for (int i = 0; i < 4; ++i) {
            const f32x4* row = (const f32x4*)&kts[(q4 * 4 + i) * QS];
            f32x2 acc = bc[0][0] * row[0].xy + bc[0][1] * row[0].zw;
            #pragma unroll
            for (int r = 1; r < 4; ++r)
                acc += bc[r][0] * row[r].xy + bc[r][1] * row[r].zw;
            kkv[i] = acc.x + acc.y;
        }
        // ---- w = Q @ kk ----
        #pragma unroll
        for (int j = 0; j < 2; ++j) {
            bc[0][j] = f32x2{dpp_mov<0x00>(kkv[2*j]), dpp_mov<0x00>(kkv[2*j+1])};
            bc[1][j] = f32x2{dpp_mov<0x55>(kkv[2*j]), dpp_mov<0x55>(kkv[2*j+1])};
            bc[2][j] = f32x2{dpp_mov<0xAA>(kkv[2*j]), dpp_mov<0xAA>(kkv[2*j+1])};
            bc[3][j] = f32x2{dpp_mov<0xFF>(kkv[2*j]), dpp_mov<0xFF>(kkv[2*j+1])};
        }
        float w[4];
        #pragma unroll
        for (int i = 0; i < 4; ++i) {
            const f32x4* row = (const f32x4*)&qs[(q4 * 4 + i) * QS];
            f32x2 acc = bc[0][0] * row[0].xy + bc[0][1] * row[0].zw;
            #pragma unroll
            for (int r = 1; r < 4; ++r)
                acc += bc[r][0] * row[r].xy + bc[r][1] * row[r].zw;
            w[i] = acc.x + acc.y;
        }
        f32x2 w2[2] = { f32x2{w[0], w[1]}, f32x2{w[2], w[3]} };

        // ---- att = softmax_k(hc . w)  (== q . kk) ----
        f32x2 lg2 = hc2[0] * w2[0] + hc2[1] * w2[1];
        float logit = rsum_quad(lg2.x + lg2.y);
        float mx  = rmax_caps(logit);
        float ex  = __expf(logit - mx);
        float att = ex * fast_rcp(rsum_caps(ex));

        // ---- column sums over the 16 gathered rows (packed) ----
        f32x2 sn2[2] = {f32x2{0,0}, f32x2{0,0}};
        f32x2 s22[2] = {f32x2{0,0}, f32x2{0,0}};
        #pragma unroll
        for (int m = 0; m < 16; ++m) {
            f32x2 v0, v1;
            if (BF) { v0 = f32x2{lo_bf(rb[m].x), hi_bf(rb[m].x)};
                      v1 = f32x2{lo_bf(rb[m].y), hi_bf(rb[m].y)}; }
            else    { v0 = f32x2{rf[m].x, rf[m].y}; v1 = f32x2{rf[m].z, rf[m].w}; }
            sn2[0] += v0;            sn2[1] += v1;
            s22[0] += v0 * v0;       s22[1] += v1 * v1;
        }

        // ---- medians ----
        float mid[4];
        if (BF) {
            unsigned a[16];
            #pragma unroll
            for (int m = 0; m < 16; ++m) a[m] = rb[m].x;
            unsigned b7, b8; pmed16(a, b7, b8);
            mid[0] = __builtin_amdgcn_fmed3f(hcs[0], lo_bf(b7), lo_bf(b8));
            mid[1] = __builtin_amdgcn_fmed3f(hcs[1], hi_bf(b7), hi_bf(b8));
            #pragma unroll
            for (int m = 0; m < 16; ++m) a[m] = rb[m].y;
            pmed16(a, b7, b8);
            mid[2] = __builtin_amdgcn_fmed3f(hcs[2], lo_bf(b7), lo_bf(b8));
            mid[3] = __builtin_amdgcn_fmed3f(hcs[3], hi_bf(b7), hi_bf(b8));
        } else {
            #pragma unroll
            for (int c = 0; c < 4; ++c) {
                float a[16];
                #pragma unroll
                for (int m = 0; m < 16; ++m)
                    a[m] = (c==0) ? rf[m].x : (c==1) ? rf[m].y : (c==2) ? rf[m].z : rf[m].w;
                mid[c] = med17f(a, hcs[c]);
            }
        }
        f32x2 mid2[2] = { f32x2{mid[0], mid[1]}, f32x2{mid[2], mid[3]} };
        #pragma unroll
        for (int p = 0; p < 2; ++p) {
            f32x2 t2 = hc2[p] * hc2[p] + s22[p];
            mid2[p] *= f32x2{fast_rsq(fmaxf(t2.x, 1e-24f)), fast_rsq(fmaxf(t2.y, 1e-24f))};
        }

        // diag[k] = (sum_m nb[m,k]) . w[k]
        f32x2 dg2 = sn2[0] * w2[0] + sn2[1] * w2[1];
        float dg  = rsum_quad(dg2.x + dg2.y);

        // cov_d = sum_k diag[k]*(hc-mid)^2  (row-independent)
        f32x2 t0 = hc2[0] - mid2[0], t1 = hc2[1] - mid2[1];
        f32x2 e0 = (dg * t0) * t0,   e1 = (dg * t1) * t1;
        f32x2 cv2[2];
        cv2[0] = f32x2{rsum_caps(e0.x), rsum_caps(e0.y)};
        cv2[1] = f32x2{rsum_caps(e1.x), rsum_caps(e1.y)};

        // dets/left, exact NaN semantics of the reference
        float lsl = 0;
        #pragma unroll
        for (int p = 0; p < 2; ++p) {
            float lrx = __logf(cv2[p].x); lrx = (lrx != lrx) ? 1e-6f : lrx;
            float lry = __logf(cv2[p].y); lry = (lry != lry) ? 1e-6f : lry;
            lsl += __logf(lrx) + __logf(lry);
        }
        float ls   = rsum_quad(lsl);
        float dets = __expf(ls);
        const float coef = 5.822108e-7f;  // 1/sqrt((2*pi)^16 / 2)
        float left = coef * fast_rsq(dets + 1e-6f);

        // ---- iterative routing (packed elementwise, scalar reduces) ----
        f32x2 ah2[2] = { att * hc2[0], att * hc2[1] };
        f32x2 ix2[2];
        ix2[0] = f32x2{rsum_caps(ah2[0].x), rsum_caps(ah2[0].y)};
        ix2[1] = f32x2{rsum_caps(ah2[1].x), rsum_caps(ah2[1].y)};

        for (int it = 0; it < iterat; ++it) {
            f32x2 d0 = ix2[0] - hc2[0], d1 = ix2[1] - hc2[1];
            f32x2 r2 = (cv2[0] * d0) * d0 + (cv2[1] * d1) * d1;
            float rs   = rsum_quad(r2.x + r2.y);
            float prob = left * __expf(-0.5f * rs);
            float p2   = rsum_caps(prob * prob);
            float pn   = prob * fast_rsq(fmaxf(p2, 1e-24f));
            pn = (pn != pn) ? 1e-6f : pn;
            f32x2 pa0 = pn * ah2[0], pa1 = pn * ah2[1];
            float den  = rsum_caps(att * pn);
            float num0 = rsum_caps(pa0.x), num1 = rsum_caps(pa0.y);
            float num2 = rsum_caps(pa1.x), num3 = rsum_caps(pa1.y);
            float rr = fast_rcp(den + 1e-9f);
            ix2[0] = f32x2{num0, num1} * rr;
            ix2[1] = f32x2{num2, num3} * rr;
        }

        // ---- x = normalize(ix); write outputs ----
        f32x2 xs2 = ix2[0] * ix2[0] + ix2[1] * ix2[1];
        float xs  = rsum_quad(xs2.x + xs2.y);
        float xinv = fast_rsq(fmaxf(xs, 1e-24f));
        f32x2 x0 = ix2[0] * xinv, x1 = ix2[1] * xinv;

        if (BF) {
            if (sub < 4) {
                __hip_bfloat16 b0 = __float2bfloat16(x0.x);
                __hip_bfloat16 b1 = __float2bfloat16(x0.y);
                __hip_bfloat16 b2 = __float2bfloat16(x1.x);
                __hip_bfloat16 b3 = __float2bfloat16(x1.y);
                uint2 o;
                o.x = (unsigned)(*(unsigned short*)&b0) | ((unsigned)(*(unsigned short*)&b1) << 16);
                o.y = (unsigned)(*(unsigned short*)&b2) | ((unsigned)(*(unsigned short*)&b3) << 16);
                *(uint2*)((char*)out + (size_t)n * 32 + q4 * 8) = o;
            }
            if (q4 == 0) {
                __hip_bfloat16 ba = __float2bfloat16(att);
                ((unsigned short*)out)[(size_t)n_nodes * KD + (size_t)n * KC + k] =
                    *(unsigned short*)&ba;
            }
        } else {
            if (sub < 4) {
                float4 o;
                o.x = x0.x; o.y = x0.y; o.z = x1.x; o.w = x1.y;
                *(float4*)((float*)out + (size_t)n * KD + q4 * 4) = o;
            }
            if (q4 == 0) ((float*)out)[(size_t)n_nodes * KD + (size_t)n * KC + k] = att;
        }
    }
}

extern "C" void kernel_launch(void* const* d_in, const int* in_sizes, int n_in,
                              void* d_out, int out_size, void* d_ws, size_t ws_size,
                              hipStream_t stream) {
    const void* h    = d_in[0];
    const int*  nbr  = (const int*)d_in[1];
    const void* qry  = d_in[2];
    const void* keyw = (const void*)d_in[3];
    const int*  iterat_p = (const int*)d_in[4];

    int n_nodes = in_sizes[0] / MD;
    int* flag = (int*)d_ws;

    detect_dtype<<<1, 64, 0, stream>>>((const unsigned short*)h, flag);

    int full = (n_nodes + 7) / 8;               // 8 nodes/block; live dtype covers all in 1 pass
    int small = full < 512 ? full : 512;        // dead-dtype path exits fast; grid-strided if live
    attn_fwd<true ><<<full,  256, 0, stream>>>(h, nbr, qry, keyw, iterat_p, flag, d_out, n_nodes);
    attn_fwd<false><<<small, 256, 0, stream>>>(h, nbr, qry, keyw, iterat_p, flag, d_out, n_nodes);
}

// Round 7
// 87.133 us; speedup vs baseline: 1.5824x; 1.1675x over previous
//
#include <hip/hip_runtime.h>
#include <hip/hip_bf16.h>

#define MD 128   // D
#define KC 8     // K capsules
#define KD 16    // DD
#define MN 16    // M neighbors
#define QS 20    // LDS row stride (floats): 16B-aligned, bank-spread

typedef _Float16 f16x2 __attribute__((ext_vector_type(2)));

static __device__ __forceinline__ float lo_bf(unsigned int w){ union{unsigned int i;float f;}c; c.i=w<<16;        return c.f; }
static __device__ __forceinline__ float hi_bf(unsigned int w){ union{unsigned int i;float f;}c; c.i=w&0xffff0000u; return c.f; }
static __device__ __forceinline__ float bf2f1(unsigned short u){ union{unsigned int i;float f;}c; c.i=((unsigned int)u)<<16; return c.f; }

template<bool BF>
static __device__ __forceinline__ float load1(const void* base, int off) {
    if (BF) return bf2f1(((const unsigned short*)base)[off]);
    return ((const float*)base)[off];
}

static __device__ __forceinline__ float fast_rsq(float x){ return __builtin_amdgcn_rsqf(x); }
static __device__ __forceinline__ float fast_rcp(float x){ return __builtin_amdgcn_rcpf(x); }

// ---- packed f16 min/max on raw bf16 bit pairs (builtins -> v_pk_min/max_f16).
// Order-exact: f16 compare order == sign-magnitude order == bf16 value order
// while no operand is in the f16 NaN/Inf bit range (|bf16| >= ~4e36). randn
// inputs have |x| <= ~6 -> huge margin. No keying needed.
static __device__ __forceinline__ unsigned phmin(unsigned a, unsigned b) {
    return __builtin_bit_cast(unsigned, __builtin_elementwise_min(
        __builtin_bit_cast(f16x2, a), __builtin_bit_cast(f16x2, b)));
}
static __device__ __forceinline__ unsigned phmax(unsigned a, unsigned b) {
    return __builtin_bit_cast(unsigned, __builtin_elementwise_max(
        __builtin_bit_cast(f16x2, a), __builtin_bit_cast(f16x2, b)));
}
static __device__ __forceinline__ void pcas(unsigned& x, unsigned& y) {
    unsigned lo = phmin(x, y), hi = phmax(x, y); x = lo; y = hi;
}
// Batcher odd-even mergesort, 8 elems, 19 CAS — two bf16 columns per op
static __device__ __forceinline__ void psort8(unsigned a[8]) {
    pcas(a[0],a[1]); pcas(a[2],a[3]); pcas(a[4],a[5]); pcas(a[6],a[7]);
    pcas(a[0],a[2]); pcas(a[1],a[3]); pcas(a[4],a[6]); pcas(a[5],a[7]);
    pcas(a[1],a[2]); pcas(a[5],a[6]);
    pcas(a[0],a[4]); pcas(a[2],a[6]); pcas(a[2],a[4]);
    pcas(a[1],a[5]); pcas(a[3],a[7]); pcas(a[3],a[5]);
    pcas(a[1],a[2]); pcas(a[3],a[4]); pcas(a[5],a[6]);
}
// b7/b8 (8th/9th smallest of 16) per packed column via merged-rank identity
static __device__ __forceinline__ void pmed16(unsigned a[16], unsigned& b7, unsigned& b8) {
    psort8(a); psort8(a + 8);
    const unsigned* u = a; const unsigned* v = a + 8;
    unsigned t7 =             phmin(u[7], v[0]);
    t7 = phmax(t7, phmin(u[6], v[1]));
    t7 = phmax(t7, phmin(u[5], v[2]));
    t7 = phmax(t7, phmin(u[4], v[3]));
    t7 = phmax(t7, phmin(u[3], v[4]));
    t7 = phmax(t7, phmin(u[2], v[5]));
    t7 = phmax(t7, phmin(u[1], v[6]));
    t7 = phmax(t7, phmin(u[0], v[7]));
    unsigned t8 = phmax(u[0], v[0]);
    t8 = phmax(t8, phmin(u[7], v[1]));
    t8 = phmax(t8, phmin(u[6], v[2]));
    t8 = phmax(t8, phmin(u[5], v[3]));
    t8 = phmax(t8, phmin(u[4], v[4]));
    t8 = phmax(t8, phmin(u[3], v[5]));
    t8 = phmax(t8, phmin(u[2], v[6]));
    t8 = phmax(t8, phmin(u[1], v[7]));
    b7 = t7; b8 = t8;
}

// ---- scalar f32 median (f32-dtype fallback path) ----
static __device__ __forceinline__ void cas(float& x, float& y) {
    float lo = fminf(x, y), hi = fmaxf(x, y); x = lo; y = hi;
}
static __device__ __forceinline__ void sort8f(float a[8]) {
    cas(a[0],a[1]); cas(a[2],a[3]); cas(a[4],a[5]); cas(a[6],a[7]);
    cas(a[0],a[2]); cas(a[1],a[3]); cas(a[4],a[6]); cas(a[5],a[7]);
    cas(a[1],a[2]); cas(a[5],a[6]);
    cas(a[0],a[4]); cas(a[2],a[6]); cas(a[2],a[4]);
    cas(a[1],a[5]); cas(a[3],a[7]); cas(a[3],a[5]);
    cas(a[1],a[2]); cas(a[3],a[4]); cas(a[5],a[6]);
}
static __device__ __forceinline__ float med17f(float a[16], float self) {
    sort8f(a); sort8f(a + 8);
    const float* u = a; const float* v = a + 8;
    float t7 =            fminf(u[7], v[0]);
    t7 = fmaxf(t7, fminf(u[6], v[1])); t7 = fmaxf(t7, fminf(u[5], v[2]));
    t7 = fmaxf(t7, fminf(u[4], v[3])); t7 = fmaxf(t7, fminf(u[3], v[4]));
    t7 = fmaxf(t7, fminf(u[2], v[5])); t7 = fmaxf(t7, fminf(u[1], v[6]));
    t7 = fmaxf(t7, fminf(u[0], v[7]));
    float t8 = fmaxf(u[0], v[0]);
    t8 = fmaxf(t8, fminf(u[7], v[1])); t8 = fmaxf(t8, fminf(u[6], v[2]));
    t8 = fmaxf(t8, fminf(u[5], v[3])); t8 = fmaxf(t8, fminf(u[4], v[4]));
    t8 = fmaxf(t8, fminf(u[3], v[5])); t8 = fmaxf(t8, fminf(u[2], v[6]));
    t8 = fmaxf(t8, fminf(u[1], v[7]));
    return __builtin_amdgcn_fmed3f(self, t7, t8);
}

// full-rate VALU lane exchange via DPP
template<int CTRL>
static __device__ __forceinline__ float dpp_mov(float v) {
    return __int_as_float(__builtin_amdgcn_update_dpp(
        0, __float_as_int(v), CTRL, 0xF, 0xF, false));
}
static __device__ __forceinline__ float rsum_quad(float v) {
    v += dpp_mov<0xB1>(v);   // quad_perm xor1
    v += dpp_mov<0x4E>(v);   // quad_perm xor2
    return v;
}
static __device__ __forceinline__ float rsum_caps(float v) {
    v += __shfl_xor(v, 4);
    v += dpp_mov<0x128>(v);  // row_ror:8 == xor8
    v += __shfl_xor(v, 16);
    return v;
}
static __device__ __forceinline__ float rmax_caps(float v) {
    v = fmaxf(v, __shfl_xor(v, 4));
    v = fmaxf(v, dpp_mov<0x128>(v));
    v = fmaxf(v, __shfl_xor(v, 16));
    return v;
}

// flag[0] = 1 if h is bf16, 0 if f32
__global__ void detect_dtype(const unsigned short* __restrict__ h, int* __restrict__ flag) {
    int l = threadIdx.x;
    float m = 0.f;
    for (int i = l; i < 1024; i += 64) {
        float v = bf2f1(h[i]);
        v = (v != v) ? 1e30f : fabsf(v);
        m = fmaxf(m, v);
    }
    #pragma unroll
    for (int off = 1; off < 64; off <<= 1) m = fmaxf(m, __shfl_xor(m, off));
    if (l == 0) flag[0] = (m < 1000.0f) ? 1 : 0;
}

template<bool BF>
__global__ __launch_bounds__(256)
void attn_fwd(const void* __restrict__ hraw,
              const int* __restrict__ nbr,
              const void* __restrict__ qry,
              const void* __restrict__ keyw,
              const int* __restrict__ iterat_p,
              const int* __restrict__ flag_p,
              void* __restrict__ out,
              int n_nodes)
{
    if (flag_p[0] != (BF ? 1 : 0)) return;  // uniform exit before the barrier

    const int tid  = threadIdx.x;
    const int wid  = tid >> 6;
    const int l    = tid & 63;
    const int sub  = l & 31;
    const int half = (l >> 5) & 1;
    const int k    = sub >> 2;
    const int q4   = sub & 3;

    int n = blockIdx.x * 8 + wid * 2 + half;
    if (n >= n_nodes) n = n_nodes - 1;  // duplicate work, identical writes

    __shared__ float qs[16 * QS];   // Q row-major
    __shared__ float kts[16 * QS];  // K^T
    {
        float qv = load1<BF>(qry, tid);
        float kv = load1<BF>(keyw, tid);
        int e = tid >> 4, f = tid & 15;
        qs [e * QS + f] = qv;
        kts[f * QS + e] = kv;
    }

    // neighbor indices: lanes 0-15 node A, 16-31 node B (upper half repeats)
    int nnb = blockIdx.x * 8 + wid * 2 + ((l >> 4) & 1);
    if (nnb >= n_nodes) nnb = n_nodes - 1;
    const int nbv = nbr[nnb * MN + (l & 15)];

    // ---- self row (4 dims/lane), per-capsule normalize ----
    float hp[4];
    if (BF) {
        uint2 w0 = ((const uint2*)hraw)[(size_t)n * 32 + sub];
        hp[0] = lo_bf(w0.x); hp[1] = hi_bf(w0.x); hp[2] = lo_bf(w0.y); hp[3] = hi_bf(w0.y);
    } else {
        float4 t = ((const float4*)hraw)[(size_t)n * 32 + sub];
        hp[0] = t.x; hp[1] = t.y; hp[2] = t.z; hp[3] = t.w;
    }
    float ss = 0;
    #pragma unroll
    for (int i = 0; i < 4; ++i) ss = fmaf(hp[i], hp[i], ss);
    ss = rsum_quad(ss);
    float inv = fast_rsq(fmaxf(ss, 1e-24f));
    float hc[4];
    #pragma unroll
    for (int i = 0; i < 4; ++i) hc[i] = hp[i] * inv;

    __syncthreads();  // Q/K staging visible (the only barrier)

    // ---- 16-row gather: ds_bpermute index broadcast (DS pipe, not VALU) ----
    const int vb = half << 6;   // byte addr of lane half*16
    uint2  rb[16]; float4 rf[16];
    #pragma unroll
    for (int m = 0; m < MN; ++m) {
        int idx = __builtin_amdgcn_ds_bpermute(vb + m * 4, nbv);
        if (BF) rb[m] = *(const uint2*) ((const char*)hraw + (((unsigned)idx << 8) + (unsigned)sub * 8u));
        else    rf[m] = *(const float4*)((const char*)hraw + (((unsigned)idx << 9) + (unsigned)sub * 16u));
    }

    // ---- broadcast hc chunks within quad (full-rate DPP, no LDS) ----
    float hcA[4][4];
    #pragma unroll
    for (int j = 0; j < 4; ++j) {
        hcA[0][j] = dpp_mov<0x00>(hc[j]);
        hcA[1][j] = dpp_mov<0x55>(hc[j]);
        hcA[2][j] = dpp_mov<0xAA>(hc[j]);
        hcA[3][j] = dpp_mov<0xFF>(hc[j]);
    }
    // kk[d] = sum_e hc[e] * K[e][d]  (reads K^T rows d = q4*4+i)
    float kk[4];
    #pragma unroll
    for (int i = 0; i < 4; ++i) {
        const float* row = &kts[(q4 * 4 + i) * QS];
        float acc = 0;
        #pragma unroll
        for (int r = 0; r < 4; ++r) {
            float4 kr = *(const float4*)(row + r * 4);
            acc = fmaf(hcA[r][0], kr.x, acc);
            acc = fmaf(hcA[r][1], kr.y, acc);
            acc = fmaf(hcA[r][2], kr.z, acc);
            acc = fmaf(hcA[r][3], kr.w, acc);
        }
        kk[i] = acc;
    }
    // w[e] = sum_f Q[e][f] * kk[f]  (reads Q rows e = q4*4+i)
    float kkA[4][4];
    #pragma unroll
    for (int j = 0; j < 4; ++j) {
        kkA[0][j] = dpp_mov<0x00>(kk[j]);
        kkA[1][j] = dpp_mov<0x55>(kk[j]);
        kkA[2][j] = dpp_mov<0xAA>(kk[j]);
        kkA[3][j] = dpp_mov<0xFF>(kk[j]);
    }
    float w[4];
    #pragma unroll
    for (int i = 0; i < 4; ++i) {
        const float* row = &qs[(q4 * 4 + i) * QS];
        float acc = 0;
        #pragma unroll
        for (int r = 0; r < 4; ++r) {
            float4 qr = *(const float4*)(row + r * 4);
            acc = fmaf(kkA[r][0], qr.x, acc);
            acc = fmaf(kkA[r][1], qr.y, acc);
            acc = fmaf(kkA[r][2], qr.z, acc);
            acc = fmaf(kkA[r][3], qr.w, acc);
        }
        w[i] = acc;
    }

    // ---- att: logit = hc . w  (== q . kk), softmax over capsules ----
    float lg = 0;
    #pragma unroll
    for (int i = 0; i < 4; ++i) lg = fmaf(hc[i], w[i], lg);
    float logit = rsum_quad(lg);
    float mx  = rmax_caps(logit);
    float ex  = __expf(logit - mx);
    float att = ex * fast_rcp(rsum_caps(ex));

    // ---- column sums (sn, s2) over the 16 gathered rows ----
    float sn[4] = {0,0,0,0}, s2[4] = {0,0,0,0};
    #pragma unroll
    for (int m = 0; m < 16; ++m) {
        float x0, x1, x2, x3;
        if (BF) { x0=lo_bf(rb[m].x); x1=hi_bf(rb[m].x); x2=lo_bf(rb[m].y); x3=hi_bf(rb[m].y); }
        else    { x0=rf[m].x; x1=rf[m].y; x2=rf[m].z; x3=rf[m].w; }
        sn[0]+=x0; sn[1]+=x1; sn[2]+=x2; sn[3]+=x3;
        s2[0]=fmaf(x0,x0,s2[0]); s2[1]=fmaf(x1,x1,s2[1]);
        s2[2]=fmaf(x2,x2,s2[2]); s2[3]=fmaf(x3,x3,s2[3]);
    }

    // ---- medians: packed f16 CAS on raw bf16 words (BF) / scalar f32 ----
    float mid[4];
    if (BF) {
        unsigned a[16];
        #pragma unroll
        for (int m = 0; m < 16; ++m) a[m] = rb[m].x;
        unsigned b7, b8; pmed16(a, b7, b8);
        mid[0] = __builtin_amdgcn_fmed3f(hc[0], lo_bf(b7), lo_bf(b8));
        mid[1] = __builtin_amdgcn_fmed3f(hc[1], hi_bf(b7), hi_bf(b8));
        #pragma unroll
        for (int m = 0; m < 16; ++m) a[m] = rb[m].y;
        pmed16(a, b7, b8);
        mid[2] = __builtin_amdgcn_fmed3f(hc[2], lo_bf(b7), lo_bf(b8));
        mid[3] = __builtin_amdgcn_fmed3f(hc[3], hi_bf(b7), hi_bf(b8));
    } else {
        #pragma unroll
        for (int c = 0; c < 4; ++c) {
            float a[16];
            #pragma unroll
            for (int m = 0; m < 16; ++m)
                a[m] = (c==0) ? rf[m].x : (c==1) ? rf[m].y : (c==2) ? rf[m].z : rf[m].w;
            mid[c] = med17f(a, hc[c]);
        }
    }
    #pragma unroll
    for (int c = 0; c < 4; ++c) {
        float t2 = fmaf(hc[c], hc[c], s2[c]);
        mid[c] *= fast_rsq(fmaxf(t2, 1e-24f));
    }

    // diag[k] = (sum_m nb[m,k]) . w[k]
    float dgl = 0;
    #pragma unroll
    for (int i = 0; i < 4; ++i) dgl = fmaf(sn[i], w[i], dgl);
    float dg = rsum_quad(dgl);

    // cov_d = sum_k diag[k]*(hc-mid)^2  (row-independent)
    float cv[4];
    #pragma unroll
    for (int i = 0; i < 4; ++i) {
        float t = hc[i] - mid[i];
        cv[i] = rsum_caps(dg * t * t);
    }

    // dets/left, exact NaN semantics of the reference
    float lsl = 0;
    #pragma unroll
    for (int i = 0; i < 4; ++i) {
        float lr = __logf(cv[i]);
        lr = (lr != lr) ? 1e-6f : lr;
        lsl += __logf(lr);
    }
    float ls   = rsum_quad(lsl);
    float dets = __expf(ls);
    const float coef = 5.822108e-7f;  // 1/sqrt((2*pi)^16 / 2)
    float left = coef * fast_rsq(dets + 1e-6f);

    // ---- iterative routing ----
    float ah[4], ix[4];
    #pragma unroll
    for (int i = 0; i < 4; ++i) ah[i] = att * hc[i];
    #pragma unroll
    for (int i = 0; i < 4; ++i) ix[i] = rsum_caps(ah[i]);

    const int iterat = iterat_p[0];
    for (int it = 0; it < iterat; ++it) {
        float rsl = 0;
        #pragma unroll
        for (int i = 0; i < 4; ++i) {
            float df = ix[i] - hc[i];
            rsl = fmaf(cv[i] * df, df, rsl);
        }
        float rs   = rsum_quad(rsl);
        float prob = left * __expf(-0.5f * rs);
        float p2   = rsum_caps(prob * prob);
        float pn   = prob * fast_rsq(fmaxf(p2, 1e-24f));
        pn = (pn != pn) ? 1e-6f : pn;
        float den = rsum_caps(att * pn);
        float num[4];
        #pragma unroll
        for (int i = 0; i < 4; ++i) num[i] = rsum_caps(pn * ah[i]);
        float rr = fast_rcp(den + 1e-9f);
        #pragma unroll
        for (int i = 0; i < 4; ++i) ix[i] = num[i] * rr;
    }

    // ---- x = normalize(ix); write outputs ----
    float xs = 0;
    #pragma unroll
    for (int i = 0; i < 4; ++i) xs = fmaf(ix[i], ix[i], xs);
    xs = rsum_quad(xs);
    float xinv = fast_rsq(fmaxf(xs, 1e-24f));

    if (BF) {
        if (sub < 4) {
            __hip_bfloat16 b0 = __float2bfloat16(ix[0] * xinv);
            __hip_bfloat16 b1 = __float2bfloat16(ix[1] * xinv);
            __hip_bfloat16 b2 = __float2bfloat16(ix[2] * xinv);
            __hip_bfloat16 b3 = __float2bfloat16(ix[3] * xinv);
            uint2 o;
            o.x = (unsigned)(*(unsigned short*)&b0) | ((unsigned)(*(unsigned short*)&b1) << 16);
            o.y = (unsigned)(*(unsigned short*)&b2) | ((unsigned)(*(unsigned short*)&b3) << 16);
            *(uint2*)((char*)out + (size_t)n * 32 + q4 * 8) = o;
        }
        if (q4 == 0) {
            __hip_bfloat16 ba = __float2bfloat16(att);
            ((unsigned short*)out)[(size_t)n_nodes * KD + (size_t)n * KC + k] =
                *(unsigned short*)&ba;
        }
    } else {
        if (sub < 4) {
            float4 o;
            o.x = ix[0] * xinv; o.y = ix[1] * xinv; o.z = ix[2] * xinv; o.w = ix[3] * xinv;
            *(float4*)((float*)out + (size_t)n * KD + q4 * 4) = o;
        }
        if (q4 == 0) ((float*)out)[(size_t)n_nodes * KD + (size_t)n * KC + k] = att;
    }
}

extern "C" void kernel_launch(void* const* d_in, const int* in_sizes, int n_in,
                              void* d_out, int out_size, void* d_ws, size_t ws_size,
                              hipStream_t stream) {
    const void* h    = d_in[0];
    const int*  nbr  = (const int*)d_in[1];
    const void* qry  = d_in[2];
    const void* keyw = (const void*)d_in[3];
    const int*  iterat_p = (const int*)d_in[4];

    int n_nodes = in_sizes[0] / MD;
    int* flag = (int*)d_ws;

    detect_dtype<<<1, 64, 0, stream>>>((const unsigned short*)h, flag);

    int blocks = (n_nodes + 7) / 8;  // 8 nodes per block (4 waves x 2)
    attn_fwd<true ><<<blocks, 256, 0, stream>>>(h, nbr, qry, keyw, iterat_p, flag, d_out, n_nodes);
    attn_fwd<false><<<blocks, 256, 0, stream>>>(h, nbr, qry, keyw, iterat_p, flag, d_out, n_nodes);
}